// Round 4
// baseline (512.575 us; speedup 1.0000x reference)
//
#include <hip/hip_runtime.h>
#include <hip/hip_bf16.h>
#include <math.h>

// Problem constants
#define MTOK 16384   // B*N tokens
#define DDIM 1024
#define EEXP 8
#define FDIM 512
#define EFK  4096    // E*F flattened K for second GEMM

typedef __attribute__((ext_vector_type(8))) short short8;   // 8 bf16 = 4 VGPRs (MFMA A/B frag)
typedef __attribute__((ext_vector_type(4))) float floatx4;  // MFMA C/D frag

__device__ __forceinline__ void gld_lds16(const void* g, void* l) {
  // async global->LDS, 16B per lane, dest = wave-uniform base + lane*16
  __builtin_amdgcn_global_load_lds((const __attribute__((address_space(1))) void*)g,
                                   (__attribute__((address_space(3))) void*)l, 16, 0, 0);
}

// Fast exact-GELU via Abramowitz-Stegun 7.1.26 erf approx (|eps| <= 1.5e-7).
__device__ __forceinline__ float gelu_fast(float v) {
  const float z  = v * 0.70710678118654752f;
  const float az = fabsf(z);
  const float t  = __builtin_amdgcn_rcpf(1.f + 0.3275911f * az);
  const float poly = t * (0.254829592f +
                     t * (-0.284496736f +
                     t * (1.421413741f +
                     t * (-1.453152027f +
                     t * 1.061405429f))));
  const float ex = __expf(-az * az);
  float erfv = 1.f - poly * ex;
  erfv = copysignf(erfv, z);
  return 0.5f * v * (1.f + erfv);
}

// ---------------- transpose + fp32->bf16 cast: in [R,C] f32 -> out [C,R] bf16, batched in z
__global__ __launch_bounds__(256) void transpose_cast_kernel(
    const float* __restrict__ in, __hip_bfloat16* __restrict__ out, int R, int C) {
  __shared__ float tile[32][33];
  const float* inb = in + (size_t)blockIdx.z * R * C;
  __hip_bfloat16* outb = out + (size_t)blockIdx.z * R * C;
  const int c0 = blockIdx.x * 32, r0 = blockIdx.y * 32;
  const int tx = threadIdx.x & 31, ty = threadIdx.x >> 5;  // 32 x 8
#pragma unroll
  for (int i = 0; i < 4; ++i)
    tile[ty + i * 8][tx] = inb[(size_t)(r0 + ty + i * 8) * C + (c0 + tx)];
  __syncthreads();
#pragma unroll
  for (int i = 0; i < 4; ++i)
    outb[(size_t)(c0 + ty + i * 8) * R + (r0 + tx)] = __float2bfloat16(tile[tx][ty + i * 8]);
}

// ---------------- router softmax (fp32) + x -> bf16 cast. One wave per token.
__global__ __launch_bounds__(256) void router_cast_kernel(
    const float* __restrict__ x, const float* __restrict__ Wr, const float* __restrict__ br,
    __hip_bfloat16* __restrict__ xbf, float* __restrict__ r) {
  const int wave = (blockIdx.x * 256 + threadIdx.x) >> 6;  // token id
  const int lane = threadIdx.x & 63;
  const float* xr = x + (size_t)wave * DDIM;
  float acc[EEXP];
#pragma unroll
  for (int e = 0; e < EEXP; ++e) acc[e] = 0.f;
#pragma unroll
  for (int i = 0; i < DDIM / 64; ++i) {
    const int d = i * 64 + lane;
    const float xv = xr[d];
    xbf[(size_t)wave * DDIM + d] = __float2bfloat16(xv);
    const float4* w4 = (const float4*)(Wr + (size_t)d * EEXP);
    const float4 w0 = w4[0], w1 = w4[1];
    acc[0] += xv * w0.x; acc[1] += xv * w0.y; acc[2] += xv * w0.z; acc[3] += xv * w0.w;
    acc[4] += xv * w1.x; acc[5] += xv * w1.y; acc[6] += xv * w1.z; acc[7] += xv * w1.w;
  }
#pragma unroll
  for (int off = 32; off; off >>= 1) {
#pragma unroll
    for (int e = 0; e < EEXP; ++e) acc[e] += __shfl_xor(acc[e], off, 64);
  }
  float mx = -1e30f;
#pragma unroll
  for (int e = 0; e < EEXP; ++e) { acc[e] += br[e]; mx = fmaxf(mx, acc[e]); }
  float s = 0.f;
#pragma unroll
  for (int e = 0; e < EEXP; ++e) { acc[e] = expf(acc[e] - mx); s += acc[e]; }
  const float inv = 1.f / s;
  if (lane < EEXP) r[(size_t)wave * EEXP + lane] = acc[lane] * inv;
}

// ============================================================================
// R4 core: 128x256 tile (M=weights, N=tokens), BK=32, 8 waves (2Mx4N, per-wave
// 64x64 -> acc 64 AGPR), TRIPLE-buffered 24 KiB LDS (72 KiB total) =>
// 2 blocks/CU (144 KiB LDS, 16 waves, 128-reg budget = 64 VGPR + 64 AGPR).
//
// R1-R3 post-mortem: three different schedules at 256^2/128KiB/1-block-per-CU
// all gave 32% MfmaUtil — resource/bubble-bound, not schedule-bound; with 8
// waves/CU every LDS-burst or wait bubble is exposed. This round restores TLP
// (2 independent blocks per CU, m114: separate waves co-schedule pipes at
// max-not-sum) and keeps all verified wins: XOR swizzle (0 conflicts), XCD
// grouping (FETCH 454->115 MB), counted vmcnt (never 0 in main loop).
//
// Per K-step t:  reads(8 ds_read_b128 from buf o0) ; stage tile t+2 into buf
// o2 (3 gld_lds) ; MFMA x16 (compiler inserts precise lgkmcnt - m97) ;
// vmcnt(3)+s_barrier ; rotate(o0,o1,o2).
//  RAW: buf[t]'s 3 loads retired by vmcnt(3) at end of t-1 (only t+1's 3
//       outstanding).  WAR: buf o2 was read two barriers ago.  Epilogue peels
//       last 2 steps with vmcnt(0).
// LDS layout (rows are 64B at BK=32, so 2 rows packed per 128B line):
//   line r' holds rows {2r', 2r'+1}; slot c (16B) holds (row&1,kchunk) with
//   c = ((row&1)*4 + kchunk) ^ (r'&7)  — XOR involution, applied inversely on
//   the per-lane GLOBAL source (rule 21: gld_lds dest stays linear).
//   Frag-read bank check: 16 lanes (rows 0..15, fixed kchunk) hit all 8
//   quad-banks twice => 2-way = free (m136).
// Frag ds_read addrs collapse to 2 per-lane base VGPRs + offset: immediates.
// ============================================================================
#define BUFB  24576                 // bytes per buffer: A 8K + B 16K
#define BOFFB 8192                  // B region offset inside buffer

#define STAGE3(O2, K0)                                                          \
  do {                                                                          \
    gld_lds16(pA  + (K0), ldsb + (O2) + (tid << 4));                            \
    gld_lds16(pB0 + (K0), ldsb + (O2) + 8192  + (tid << 4));                    \
    gld_lds16(pB1 + (K0), ldsb + (O2) + 16384 + (tid << 4));                    \
  } while (0)

#define READS8(O0)                                                              \
  _Pragma("unroll") for (int i_ = 0; i_ < 4; ++i_)                              \
    af[i_] = *(const short8*)(ldsb + (O0) + laneA + i_ * 1024);                 \
  _Pragma("unroll") for (int j_ = 0; j_ < 4; ++j_)                              \
    bf[j_] = *(const short8*)(ldsb + (O0) + laneB + j_ * 1024);

#define MFMA16                                                                  \
  _Pragma("unroll") for (int i_ = 0; i_ < 4; ++i_)                              \
    _Pragma("unroll") for (int j_ = 0; j_ < 4; ++j_)                            \
      acc[i_][j_] = __builtin_amdgcn_mfma_f32_16x16x32_bf16(                    \
          af[i_], bf[j_], acc[i_][j_], 0, 0, 0);

#define GEMM_CORE(NT)                                                           \
  STAGE3(0, 0);                                                                 \
  STAGE3(BUFB, 32);                                                             \
  asm volatile("s_waitcnt vmcnt(3)\n\ts_barrier" ::: "memory");                 \
  {                                                                             \
    int o0 = 0, o1 = BUFB, o2 = 2 * BUFB;                                       \
    for (int kt = 0; kt < (NT) - 2; ++kt) {                                     \
      READS8(o0);                                                               \
      STAGE3(o2, (kt + 2) * 32);                                                \
      __builtin_amdgcn_s_setprio(1);                                            \
      MFMA16;                                                                   \
      __builtin_amdgcn_s_setprio(0);                                            \
      __builtin_amdgcn_sched_barrier(0);                                        \
      asm volatile("s_waitcnt vmcnt(3)\n\ts_barrier" ::: "memory");             \
      const int t_ = o0; o0 = o1; o1 = o2; o2 = t_;                             \
    }                                                                           \
    READS8(o0);                                                                 \
    __builtin_amdgcn_s_setprio(1);                                              \
    MFMA16;                                                                     \
    __builtin_amdgcn_s_setprio(0);                                              \
    __builtin_amdgcn_sched_barrier(0);                                          \
    asm volatile("s_waitcnt vmcnt(0)\n\ts_barrier" ::: "memory");               \
    READS8(o1);                                                                 \
    __builtin_amdgcn_s_setprio(1);                                              \
    MFMA16;                                                                     \
    __builtin_amdgcn_s_setprio(0);                                              \
  }

// Per-thread staging source precompute (inverse swizzle on global rows):
//   LDS byte pos p (16B slots): r' = p>>3, c = p&7, u = c ^ (r'&7);
//   holds global (row = 2r' + (u>>2), kchunk = u&3).
#define STAGE_PTR(gbase, LD, posv)                                              \
  ((gbase) + (size_t)(2 * ((posv) >> 3) + ((((posv) & 7) ^ (((posv) >> 3) & 7)) >> 2)) * (LD) \
           + ((((posv) & 7) ^ (((posv) >> 3) & 7)) & 3) * 8)

// ---------------- GEMM 1: Hs[tok][e*F+f] = bf16( gelu(x @ W1[e] + b1[e]) * r[tok,e] )
// Grid: 2048 blocks = strip-major per XCD: xcd=bid&7, t=bid>>3; strip=(t>>5)*8+xcd,
// em=t&31 (e=em>>2, mb=em&3). All 32 (e,mb) blocks of one token strip run
// concurrently on one XCD -> x strip fetched once; W1t (8MB) L3-resident.
__global__ __launch_bounds__(512, 4) void gemm_h_kernel(
    const __hip_bfloat16* __restrict__ A, const __hip_bfloat16* __restrict__ W1t,
    const float* __restrict__ b1, const float* __restrict__ r,
    __hip_bfloat16* __restrict__ Hs) {
  const int bid = blockIdx.x;
  const int xcd = bid & 7, t = bid >> 3;
  const int strip = (t >> 5) * 8 + xcd;       // 0..63
  const int em = t & 31, e = em >> 2, mb = em & 3;
  const int T0 = strip * 256, F0 = mb * 128;

  __shared__ char ldsb[3 * BUFB];   // 72 KiB -> 2 blocks/CU

  const int tid = threadIdx.x, lane = tid & 63, wid = tid >> 6;
  const int wr = wid >> 2, wc = wid & 3;       // 2 x 4 wave grid
  const int lanem = lane & 15, laneq = lane >> 4;
  const int cswz = (((lanem & 1) << 2) | laneq) ^ (lanem >> 1);
  const int laneA = (lanem >> 1) * 128 + cswz * 16 + wr * 4096;
  const int laneB = BOFFB + (lanem >> 1) * 128 + cswz * 16 + wc * 4096;

  const __hip_bfloat16* gA = W1t + (size_t)e * FDIM * DDIM + (size_t)F0 * DDIM;
  const __hip_bfloat16* gB = A + (size_t)T0 * DDIM;
  const __hip_bfloat16* pA  = STAGE_PTR(gA, DDIM, tid);
  const __hip_bfloat16* pB0 = STAGE_PTR(gB, DDIM, tid);
  const __hip_bfloat16* pB1 = STAGE_PTR(gB, DDIM, tid + 512);

  floatx4 acc[4][4];
#pragma unroll
  for (int i = 0; i < 4; ++i)
#pragma unroll
    for (int j = 0; j < 4; ++j) acc[i][j] = (floatx4){0.f, 0.f, 0.f, 0.f};
  short8 af[4], bf[4];

  GEMM_CORE(DDIM / 32);

  // epilogue: bias -> fast exact-gelu -> router scale -> packed bf16x4 store
#pragma unroll
  for (int nj = 0; nj < 4; ++nj) {
    const int tok = T0 + wc * 64 + nj * 16 + lanem;
    const float rv = r[(size_t)tok * EEXP + e];
#pragma unroll
    for (int mi = 0; mi < 4; ++mi) {
      const int f = F0 + wr * 64 + mi * 16 + laneq * 4;    // 4 consecutive f
      const float4 b4 = *(const float4*)(b1 + e * FDIM + f);
      union { ushort4 u; __hip_bfloat16 h[4]; } pk;
      pk.h[0] = __float2bfloat16(gelu_fast(acc[mi][nj][0] + b4.x) * rv);
      pk.h[1] = __float2bfloat16(gelu_fast(acc[mi][nj][1] + b4.y) * rv);
      pk.h[2] = __float2bfloat16(gelu_fast(acc[mi][nj][2] + b4.z) * rv);
      pk.h[3] = __float2bfloat16(gelu_fast(acc[mi][nj][3] + b4.w) * rv);
      *(ushort4*)(Hs + (size_t)tok * EFK + e * FDIM + f) = pk.u;
    }
  }
}

// ---------------- GEMM 2: out[tok][d] = Hs[tok,:] @ W2flat[:,d] + sum_e r[tok,e]*b2[e,d]
// Grid: 512 blocks = exactly 2/CU, one full round. xcd=bid&7, t=bid>>3;
// strip=(t>>3)*8+xcd, mb=t&7. The 8 d-blocks of a strip are dispatch-adjacent
// on one XCD -> strip's Hs rows fetched once, k-synchronized sweep.
__global__ __launch_bounds__(512, 4) void gemm_out_kernel(
    const __hip_bfloat16* __restrict__ Hs, const __hip_bfloat16* __restrict__ W2t,
    const float* __restrict__ b2, const float* __restrict__ r,
    float* __restrict__ out) {
  const int bid = blockIdx.x;
  const int xcd = bid & 7, t = bid >> 3;
  const int strip = (t >> 3) * 8 + xcd;       // 0..63
  const int mb = t & 7;                       // d block
  const int T0 = strip * 256, D0 = mb * 128;

  __shared__ char ldsb[3 * BUFB];   // 72 KiB -> 2 blocks/CU

  const int tid = threadIdx.x, lane = tid & 63, wid = tid >> 6;
  const int wr = wid >> 2, wc = wid & 3;
  const int lanem = lane & 15, laneq = lane >> 4;
  const int cswz = (((lanem & 1) << 2) | laneq) ^ (lanem >> 1);
  const int laneA = (lanem >> 1) * 128 + cswz * 16 + wr * 4096;
  const int laneB = BOFFB + (lanem >> 1) * 128 + cswz * 16 + wc * 4096;

  const __hip_bfloat16* gA = W2t + (size_t)D0 * EFK;
  const __hip_bfloat16* gB = Hs + (size_t)T0 * EFK;
  const __hip_bfloat16* pA  = STAGE_PTR(gA, EFK, tid);
  const __hip_bfloat16* pB0 = STAGE_PTR(gB, EFK, tid);
  const __hip_bfloat16* pB1 = STAGE_PTR(gB, EFK, tid + 512);

  floatx4 acc[4][4];
#pragma unroll
  for (int i = 0; i < 4; ++i)
#pragma unroll
    for (int j = 0; j < 4; ++j) acc[i][j] = (floatx4){0.f, 0.f, 0.f, 0.f};
  short8 af[4], bf[4];

  GEMM_CORE(EFK / 32);

  // epilogue: combined bias sum_e r[tok,e]*b2[e,d], float4 store
#pragma unroll
  for (int mi = 0; mi < 4; ++mi) {
    const int d0 = D0 + wr * 64 + mi * 16 + laneq * 4;     // 4 consecutive d
    float4 b2v[EEXP];
#pragma unroll
    for (int e = 0; e < EEXP; ++e) b2v[e] = *(const float4*)(b2 + e * DDIM + d0);
#pragma unroll
    for (int nj = 0; nj < 4; ++nj) {
      const int tok = T0 + wc * 64 + nj * 16 + lanem;
      const float4* r4 = (const float4*)(r + (size_t)tok * EEXP);
      const float4 r0 = r4[0], r1 = r4[1];
      const float rv[EEXP] = {r0.x, r0.y, r0.z, r0.w, r1.x, r1.y, r1.z, r1.w};
      float bx = 0.f, by = 0.f, bz = 0.f, bw = 0.f;
#pragma unroll
      for (int e = 0; e < EEXP; ++e) {
        bx += rv[e] * b2v[e].x; by += rv[e] * b2v[e].y;
        bz += rv[e] * b2v[e].z; bw += rv[e] * b2v[e].w;
      }
      float4 o;
      o.x = acc[mi][nj][0] + bx; o.y = acc[mi][nj][1] + by;
      o.z = acc[mi][nj][2] + bz; o.w = acc[mi][nj][3] + bw;
      *(float4*)(out + (size_t)tok * DDIM + d0) = o;
    }
  }
}

extern "C" void kernel_launch(void* const* d_in, const int* in_sizes, int n_in,
                              void* d_out, int out_size, void* d_ws, size_t ws_size,
                              hipStream_t stream) {
  const float* x  = (const float*)d_in[0];
  const float* W1 = (const float*)d_in[1];
  const float* b1 = (const float*)d_in[2];
  const float* W2 = (const float*)d_in[3];
  const float* b2 = (const float*)d_in[4];
  const float* Wr = (const float*)d_in[5];
  const float* br = (const float*)d_in[6];
  float* out = (float*)d_out;

  char* ws = (char*)d_ws;
  __hip_bfloat16* xbf = (__hip_bfloat16*)(ws);                            // 32 MB
  __hip_bfloat16* W1t = (__hip_bfloat16*)(ws + (32u << 20));              // 8 MB  [E][F][D]
  __hip_bfloat16* W2t = (__hip_bfloat16*)(ws + (40u << 20));              // 8 MB  [D][E*F]
  float*          r   = (float*)(ws + (48u << 20));                       // 0.5 MB [MTOK][E]
  __hip_bfloat16* Hs  = (__hip_bfloat16*)(ws + (48u << 20) + (1u << 19)); // 128 MB [MTOK][E*F]

  // W1 [E][D][F] -> W1t [E][F][D]
  transpose_cast_kernel<<<dim3(FDIM / 32, DDIM / 32, EEXP), 256, 0, stream>>>(W1, W1t, DDIM, FDIM);
  // W2 [E*F][D] -> W2t [D][E*F]
  transpose_cast_kernel<<<dim3(DDIM / 32, EFK / 32, 1), 256, 0, stream>>>(W2, W2t, EFK, DDIM);
  // router softmax + x cast
  router_cast_kernel<<<MTOK / 4, 256, 0, stream>>>(x, Wr, br, xbf, r);
  // stage 1 grouped GEMM (+gelu, +router scale): 128-f x 256-tok tiles
  gemm_h_kernel<<<dim3((MTOK / 256) * (FDIM / 128) * EEXP), 512, 0, stream>>>(xbf, W1t, b1, r, Hs);
  // stage 2 GEMM (+combined bias): 128-d x 256-tok tiles, XCD-grouped strips
  gemm_out_kernel<<<dim3((MTOK / 256) * (DDIM / 128)), 512, 0, stream>>>(Hs, W2t, b2, r, out);
}

// Round 5
// 478.566 us; speedup vs baseline: 1.0711x; 1.0711x over previous
//
#include <hip/hip_runtime.h>
#include <hip/hip_bf16.h>
#include <math.h>

// Problem constants
#define MTOK 16384   // B*N tokens
#define DDIM 1024
#define EEXP 8
#define FDIM 512
#define EFK  4096    // E*F flattened K for second GEMM

typedef __attribute__((ext_vector_type(8))) short short8;   // 8 bf16 = 4 VGPRs (MFMA A/B frag)
typedef __attribute__((ext_vector_type(4))) float floatx4;  // MFMA C/D frag

__device__ __forceinline__ void gld_lds16(const void* g, void* l) {
  // async global->LDS, 16B per lane, dest = wave-uniform base + lane*16
  __builtin_amdgcn_global_load_lds((const __attribute__((address_space(1))) void*)g,
                                   (__attribute__((address_space(3))) void*)l, 16, 0, 0);
}

// Fast exact-GELU via Abramowitz-Stegun 7.1.26 erf approx (|eps| <= 1.5e-7).
__device__ __forceinline__ float gelu_fast(float v) {
  const float z  = v * 0.70710678118654752f;
  const float az = fabsf(z);
  const float t  = __builtin_amdgcn_rcpf(1.f + 0.3275911f * az);
  const float poly = t * (0.254829592f +
                     t * (-0.284496736f +
                     t * (1.421413741f +
                     t * (-1.453152027f +
                     t * 1.061405429f))));
  const float ex = __expf(-az * az);
  float erfv = 1.f - poly * ex;
  erfv = copysignf(erfv, z);
  return 0.5f * v * (1.f + erfv);
}

// ---------------- transpose + fp32->bf16 cast: in [R,C] f32 -> out [C,R] bf16, batched in z
__global__ __launch_bounds__(256) void transpose_cast_kernel(
    const float* __restrict__ in, __hip_bfloat16* __restrict__ out, int R, int C) {
  __shared__ float tile[32][33];
  const float* inb = in + (size_t)blockIdx.z * R * C;
  __hip_bfloat16* outb = out + (size_t)blockIdx.z * R * C;
  const int c0 = blockIdx.x * 32, r0 = blockIdx.y * 32;
  const int tx = threadIdx.x & 31, ty = threadIdx.x >> 5;  // 32 x 8
#pragma unroll
  for (int i = 0; i < 4; ++i)
    tile[ty + i * 8][tx] = inb[(size_t)(r0 + ty + i * 8) * C + (c0 + tx)];
  __syncthreads();
#pragma unroll
  for (int i = 0; i < 4; ++i)
    outb[(size_t)(c0 + ty + i * 8) * R + (r0 + tx)] = __float2bfloat16(tile[tx][ty + i * 8]);
}

// ---------------- router softmax (fp32) + x -> bf16 cast. One wave per token.
__global__ __launch_bounds__(256) void router_cast_kernel(
    const float* __restrict__ x, const float* __restrict__ Wr, const float* __restrict__ br,
    __hip_bfloat16* __restrict__ xbf, float* __restrict__ r) {
  const int wave = (blockIdx.x * 256 + threadIdx.x) >> 6;  // token id
  const int lane = threadIdx.x & 63;
  const float* xr = x + (size_t)wave * DDIM;
  float acc[EEXP];
#pragma unroll
  for (int e = 0; e < EEXP; ++e) acc[e] = 0.f;
#pragma unroll
  for (int i = 0; i < DDIM / 64; ++i) {
    const int d = i * 64 + lane;
    const float xv = xr[d];
    xbf[(size_t)wave * DDIM + d] = __float2bfloat16(xv);
    const float4* w4 = (const float4*)(Wr + (size_t)d * EEXP);
    const float4 w0 = w4[0], w1 = w4[1];
    acc[0] += xv * w0.x; acc[1] += xv * w0.y; acc[2] += xv * w0.z; acc[3] += xv * w0.w;
    acc[4] += xv * w1.x; acc[5] += xv * w1.y; acc[6] += xv * w1.z; acc[7] += xv * w1.w;
  }
#pragma unroll
  for (int off = 32; off; off >>= 1) {
#pragma unroll
    for (int e = 0; e < EEXP; ++e) acc[e] += __shfl_xor(acc[e], off, 64);
  }
  float mx = -1e30f;
#pragma unroll
  for (int e = 0; e < EEXP; ++e) { acc[e] += br[e]; mx = fmaxf(mx, acc[e]); }
  float s = 0.f;
#pragma unroll
  for (int e = 0; e < EEXP; ++e) { acc[e] = expf(acc[e] - mx); s += acc[e]; }
  const float inv = 1.f / s;
  if (lane < EEXP) r[(size_t)wave * EEXP + lane] = acc[lane] * inv;
}

// ============================================================================
// R5 core: faithful m201 deep-pipeline port. 256x256 tile, BK=64, 8 waves
// (2M x 4N), dbuf 128 KiB, 4 phases/K-tile, STAGING 1.5 K-TILES AHEAD with
// ONE vmcnt(6) gate per K-tile (never 0 mid-loop) — the un-replicated m201
// elements vs R2-R4 (all ~30% MfmaUtil): deep prefetch, single fine gate,
// lgkm(8) pre-barrier hint, read-free ph4 (B register-held whole tile).
//
// Steady state, tile t in buf p=t&1 (granules: a0=A rows 0-63 group, a1=A
// 64-127 group, b0/b1 = B quarters; 16 KiB each = 2 gld_lds/thread):
//  ph1 (Q0,0): reads A0(8)+B0(4); stage q.A1 <- t+1.a1 ; lgkm(8); bar;
//              lgkm(0); MFMA16; bar.
//  ph2 (Q0,1): reads B1(4);       stage p.A0 <- t+2.a0 ; bar; lgkm(0); MFMA16; bar.
//  ph3 (Q1,1): reads A1(8);       stage p.B1 <- t+2.b1 ; bar; lgkm(0); MFMA16; bar.
//  ph4 (Q1,0): no reads;          stage p.B0 <- t+2.b0 ; vmcnt(6); bar; MFMA16; bar.
// WAR safety of mid-tile stores into p: each region's LAST ds_read is >=1
// phase (2 barriers) before its re-stage (A0 read ph1 only; B1 read ph2,
// held in regs ph3; B0 read ph1, held in regs through ph4). t+1.a1 goes to
// the idle buffer q. FIFO gate: at ph4-of-t, outstanding = {t+2.a0,b1,b0}
// = 6 loads -> vmcnt(6) proves t+1 fully resident before its ph1 reads.
// Prologue stages 7 granules (t0 full + t1 a0,b0,b1), vmcnt(6). Epilogue:
// kt=NT-2 gates vmcnt(0); kt=NT-1 stages nothing.
// Swizzle (rule 21, R1-verified 0 conflicts): LDS dest linear; per-lane
// GLOBAL source chunk pre-swizzled (chunk = l7 ^ l3) so LDS[row][c] holds
// G[row][c ^ (row&7)]; frag reads XOR the same (row&7) back.
// ============================================================================
#define BUFSZ 65536
#define AOFF  0
#define BOFF  32768

#define STAGE_A(Q1, QM, K0)                                                        \
  do {                                                                             \
    _Pragma("unroll") for (int r_ = 0; r_ < 2; ++r_) {                             \
      gld_lds16(gA + (size_t)(r_ * 128 + (QM) * 64 + wid * 8 + l3) * LDA_ +        \
                    (K0) + ((l7 ^ l3) * 8),                                        \
                ldsb + (Q1) * BUFSZ + AOFF + (QM) * 16384 +                        \
                    (r_ * 64 + wid * 8) * 128);                                    \
    }                                                                              \
  } while (0)

#define STAGE_B(Q1, QN, K0)                                                        \
  do {                                                                             \
    _Pragma("unroll") for (int r_ = 0; r_ < 2; ++r_) {                             \
      const int lin_ = r_ * 64 + wid * 8 + l3;                                     \
      gld_lds16(gB + (size_t)((lin_ >> 5) * 64 + (QN) * 32 + (lin_ & 31)) * LDB_ + \
                    (K0) + ((l7 ^ l3) * 8),                                        \
                ldsb + (Q1) * BUFSZ + BOFF + (QN) * 16384 +                        \
                    (r_ * 64 + wid * 8) * 128);                                    \
    }                                                                              \
  } while (0)

#define READS_AF(P, QM)                                                            \
  _Pragma("unroll") for (int i_ = 0; i_ < 4; ++i_)                                 \
    _Pragma("unroll") for (int k_ = 0; k_ < 2; ++k_)                               \
      af[i_][k_] = *(const short8*)(ldsb + (P) * BUFSZ + AOFF +                    \
          (QM) * 16384 + (wr * 64 + i_ * 16 + lanem) * 128 +                       \
          (((k_ * 4 + laneq) ^ swz) * 16));

#define READS_BH(P, QN)                                                            \
  _Pragma("unroll") for (int j_ = 0; j_ < 2; ++j_)                                 \
    _Pragma("unroll") for (int k_ = 0; k_ < 2; ++k_)                               \
      bf[(QN) * 2 + j_][k_] = *(const short8*)(ldsb + (P) * BUFSZ + BOFF +         \
          (QN) * 16384 + (wc * 32 + j_ * 16 + lanem) * 128 +                       \
          (((k_ * 4 + laneq) ^ swz) * 16));

#define MFMA_Q(QM, QN)                                                             \
  __builtin_amdgcn_s_setprio(1);                                                   \
  _Pragma("unroll") for (int k_ = 0; k_ < 2; ++k_)                                 \
    _Pragma("unroll") for (int i_ = 0; i_ < 4; ++i_)                               \
      _Pragma("unroll") for (int j_ = 0; j_ < 2; ++j_)                             \
        acc[(QM) * 4 + i_][(QN) * 2 + j_] =                                        \
            __builtin_amdgcn_mfma_f32_16x16x32_bf16(                               \
                af[i_][k_], bf[(QN) * 2 + j_][k_],                                 \
                acc[(QM) * 4 + i_][(QN) * 2 + j_], 0, 0, 0);                       \
  __builtin_amdgcn_s_setprio(0);

#define LGKM0                                                                      \
  asm volatile("s_waitcnt lgkmcnt(0)" ::: "memory");                               \
  __builtin_amdgcn_sched_barrier(0)

#define GEMM_CORE(NT)                                                              \
  STAGE_A(0, 0, 0); STAGE_B(0, 0, 0); STAGE_B(0, 1, 0); STAGE_A(0, 1, 0);          \
  STAGE_A(1, 0, 64); STAGE_B(1, 0, 64); STAGE_B(1, 1, 64);                         \
  asm volatile("s_waitcnt vmcnt(6)\n\ts_barrier" ::: "memory");                    \
  for (int kt = 0; kt < (NT); ++kt) {                                              \
    const int p_ = kt & 1, q_ = p_ ^ 1;                                            \
    /* ---- ph1 : Q(0,0) ---- */                                                   \
    READS_AF(p_, 0);                                                               \
    READS_BH(p_, 0);                                                               \
    if (kt + 1 < (NT)) STAGE_A(q_, 1, (kt + 1) * 64);                              \
    asm volatile("s_waitcnt lgkmcnt(8)" ::: "memory");                             \
    __builtin_amdgcn_sched_barrier(0);                                             \
    __builtin_amdgcn_s_barrier();                                                  \
    LGKM0;                                                                         \
    MFMA_Q(0, 0);                                                                  \
    __builtin_amdgcn_s_barrier();                                                  \
    /* ---- ph2 : Q(0,1) ---- */                                                   \
    READS_BH(p_, 1);                                                               \
    if (kt + 2 < (NT)) STAGE_A(p_, 0, (kt + 2) * 64);                              \
    __builtin_amdgcn_s_barrier();                                                  \
    LGKM0;                                                                         \
    MFMA_Q(0, 1);                                                                  \
    __builtin_amdgcn_s_barrier();                                                  \
    /* ---- ph3 : Q(1,1) ---- */                                                   \
    READS_AF(p_, 1);                                                               \
    if (kt + 2 < (NT)) STAGE_B(p_, 1, (kt + 2) * 64);                              \
    __builtin_amdgcn_s_barrier();                                                  \
    LGKM0;                                                                         \
    MFMA_Q(1, 1);                                                                  \
    __builtin_amdgcn_s_barrier();                                                  \
    /* ---- ph4 : Q(1,0), read-free ---- */                                        \
    if (kt + 2 < (NT)) {                                                           \
      STAGE_B(p_, 0, (kt + 2) * 64);                                               \
      asm volatile("s_waitcnt vmcnt(6)\n\ts_barrier" ::: "memory");                \
    } else if (kt + 1 < (NT)) {                                                    \
      asm volatile("s_waitcnt vmcnt(0)\n\ts_barrier" ::: "memory");                \
    } else {                                                                       \
      __builtin_amdgcn_s_barrier();                                                \
    }                                                                              \
    MFMA_Q(1, 0);                                                                  \
    __builtin_amdgcn_s_barrier();                                                  \
  }

// ---------------- GEMM 1: Hs[tok][e*F+f] = bf16( gelu(x @ W1[e] + b1[e]) * r[tok,e] )
// Grid: 1024 blocks = e(8) x fb(2) x strip(64); strip fastest so the 16 blocks
// sharing a token strip are 64 apart in bid -> same XCD (64%8==0) -> x strip
// L2-resident; each (e,fb) weight slice dispatch-adjacent.
__global__ __launch_bounds__(512, 2) void gemm_h_kernel(
    const __hip_bfloat16* __restrict__ A, const __hip_bfloat16* __restrict__ W1t,
    const float* __restrict__ b1, const float* __restrict__ r,
    __hip_bfloat16* __restrict__ Hs) {
  const int bid = blockIdx.x;
  const int strip = bid & 63, fb = (bid >> 6) & 1, e = bid >> 7;
  const int T0 = strip * 256, F0 = fb * 256;

  __shared__ char ldsb[2 * BUFSZ];   // 128 KiB

  const int tid = threadIdx.x, lane = tid & 63, wid = tid >> 6;
  const int wr = wid >> 2, wc = wid & 3;       // 2 x 4 wave grid
  const int lanem = lane & 15, laneq = lane >> 4;
  const int l3 = lane >> 3, l7 = lane & 7;     // staging lane decompose
  const int swz = lanem & 7;
  const int LDA_ = DDIM, LDB_ = DDIM;

  const __hip_bfloat16* gA = W1t + (size_t)e * FDIM * DDIM + (size_t)F0 * DDIM;
  const __hip_bfloat16* gB = A + (size_t)T0 * DDIM;

  floatx4 acc[8][4];
#pragma unroll
  for (int i = 0; i < 8; ++i)
#pragma unroll
    for (int j = 0; j < 4; ++j) acc[i][j] = (floatx4){0.f, 0.f, 0.f, 0.f};
  short8 af[4][2], bf[4][2];

  GEMM_CORE(DDIM / 64);

  // epilogue: bias -> fast exact-gelu -> router scale -> packed bf16x4 store
#pragma unroll
  for (int nj = 0; nj < 4; ++nj) {
    const int tok = T0 + wc * 64 + nj * 16 + lanem;
    const float rv = r[(size_t)tok * EEXP + e];
#pragma unroll
    for (int mi = 0; mi < 8; ++mi) {
      const int f = F0 + wr * 128 + mi * 16 + laneq * 4;   // 4 consecutive f
      const float4 b4 = *(const float4*)(b1 + e * FDIM + f);
      union { ushort4 u; __hip_bfloat16 h[4]; } pk;
      pk.h[0] = __float2bfloat16(gelu_fast(acc[mi][nj][0] + b4.x) * rv);
      pk.h[1] = __float2bfloat16(gelu_fast(acc[mi][nj][1] + b4.y) * rv);
      pk.h[2] = __float2bfloat16(gelu_fast(acc[mi][nj][2] + b4.z) * rv);
      pk.h[3] = __float2bfloat16(gelu_fast(acc[mi][nj][3] + b4.w) * rv);
      *(ushort4*)(Hs + (size_t)tok * EFK + e * FDIM + f) = pk.u;
    }
  }
}

// ---------------- GEMM 2: out[tok][d] = Hs[tok,:] @ W2flat[:,d] + sum_e r[tok,e]*b2[e,d]
// Grid: 256 blocks; decode puts the 4 d-quarter blocks of one token strip on
// the SAME XCD (bid%8 == strip%8) -> the strip's Hs rows L2-shared 4x.
__global__ __launch_bounds__(512, 2) void gemm_out_kernel(
    const __hip_bfloat16* __restrict__ Hs, const __hip_bfloat16* __restrict__ W2t,
    const float* __restrict__ b2, const float* __restrict__ r,
    float* __restrict__ out) {
  const int bid = blockIdx.x;
  const int strip = (bid >> 5) * 8 + (bid & 7);   // 0..63 token strip
  const int dq = (bid >> 3) & 3;                  // d quarter
  const int T0 = strip * 256, D0 = dq * 256;

  __shared__ char ldsb[2 * BUFSZ];   // 128 KiB

  const int tid = threadIdx.x, lane = tid & 63, wid = tid >> 6;
  const int wr = wid >> 2, wc = wid & 3;
  const int lanem = lane & 15, laneq = lane >> 4;
  const int l3 = lane >> 3, l7 = lane & 7;
  const int swz = lanem & 7;
  const int LDA_ = EFK, LDB_ = EFK;

  const __hip_bfloat16* gA = W2t + (size_t)D0 * EFK;
  const __hip_bfloat16* gB = Hs + (size_t)T0 * EFK;

  floatx4 acc[8][4];
#pragma unroll
  for (int i = 0; i < 8; ++i)
#pragma unroll
    for (int j = 0; j < 4; ++j) acc[i][j] = (floatx4){0.f, 0.f, 0.f, 0.f};
  short8 af[4][2], bf[4][2];

  GEMM_CORE(EFK / 64);

  // epilogue: combined bias sum_e r[tok,e]*b2[e,d], float4 store
#pragma unroll
  for (int mi = 0; mi < 8; ++mi) {
    const int d0 = D0 + wr * 128 + mi * 16 + laneq * 4;    // 4 consecutive d
    float4 b2v[EEXP];
#pragma unroll
    for (int e = 0; e < EEXP; ++e) b2v[e] = *(const float4*)(b2 + e * DDIM + d0);
#pragma unroll
    for (int nj = 0; nj < 4; ++nj) {
      const int tok = T0 + wc * 64 + nj * 16 + lanem;
      const float4* r4 = (const float4*)(r + (size_t)tok * EEXP);
      const float4 r0 = r4[0], r1 = r4[1];
      const float rv[EEXP] = {r0.x, r0.y, r0.z, r0.w, r1.x, r1.y, r1.z, r1.w};
      float bx = 0.f, by = 0.f, bz = 0.f, bw = 0.f;
#pragma unroll
      for (int e = 0; e < EEXP; ++e) {
        bx += rv[e] * b2v[e].x; by += rv[e] * b2v[e].y;
        bz += rv[e] * b2v[e].z; bw += rv[e] * b2v[e].w;
      }
      float4 o;
      o.x = acc[mi][nj][0] + bx; o.y = acc[mi][nj][1] + by;
      o.z = acc[mi][nj][2] + bz; o.w = acc[mi][nj][3] + bw;
      *(float4*)(out + (size_t)tok * DDIM + d0) = o;
    }
  }
}

extern "C" void kernel_launch(void* const* d_in, const int* in_sizes, int n_in,
                              void* d_out, int out_size, void* d_ws, size_t ws_size,
                              hipStream_t stream) {
  const float* x  = (const float*)d_in[0];
  const float* W1 = (const float*)d_in[1];
  const float* b1 = (const float*)d_in[2];
  const float* W2 = (const float*)d_in[3];
  const float* b2 = (const float*)d_in[4];
  const float* Wr = (const float*)d_in[5];
  const float* br = (const float*)d_in[6];
  float* out = (float*)d_out;

  char* ws = (char*)d_ws;
  __hip_bfloat16* xbf = (__hip_bfloat16*)(ws);                            // 32 MB
  __hip_bfloat16* W1t = (__hip_bfloat16*)(ws + (32u << 20));              // 8 MB  [E][F][D]
  __hip_bfloat16* W2t = (__hip_bfloat16*)(ws + (40u << 20));              // 8 MB  [D][E*F]
  float*          r   = (float*)(ws + (48u << 20));                       // 0.5 MB [MTOK][E]
  __hip_bfloat16* Hs  = (__hip_bfloat16*)(ws + (48u << 20) + (1u << 19)); // 128 MB [MTOK][E*F]

  // W1 [E][D][F] -> W1t [E][F][D]
  transpose_cast_kernel<<<dim3(FDIM / 32, DDIM / 32, EEXP), 256, 0, stream>>>(W1, W1t, DDIM, FDIM);
  // W2 [E*F][D] -> W2t [D][E*F]
  transpose_cast_kernel<<<dim3(DDIM / 32, EFK / 32, 1), 256, 0, stream>>>(W2, W2t, EFK, DDIM);
  // router softmax + x cast
  router_cast_kernel<<<MTOK / 4, 256, 0, stream>>>(x, Wr, br, xbf, r);
  // stage 1 grouped GEMM (+gelu, +router scale): 256-f x 256-tok tiles
  gemm_h_kernel<<<dim3((MTOK / 256) * (FDIM / 256) * EEXP), 512, 0, stream>>>(xbf, W1t, b1, r, Hs);
  // stage 2 GEMM (+combined bias): 256-d x 256-tok tiles, XCD-grouped strips
  gemm_out_kernel<<<dim3((MTOK / 256) * (DDIM / 256)), 512, 0, stream>>>(Hs, W2t, b2, r, out);
}